// Round 2
// baseline (257.842 us; speedup 1.0000x reference)
//
#include <hip/hip_runtime.h>
#include <float.h>

// Problem constants (fixed by reference): B=32 L=1024 D=128 K=1024
#define NTOK 32768
#define DDIM 128
#define KCODES 1024
#define TT 64     // tokens per block
#define KC 64     // codes per K-chunk
#define TP 72     // LDS pitch — conflict-free float4 reads

// Optimization barrier: prevents fma-contraction / reassociation across it,
// so we can replicate numpy's exact fp32 rounding sequence.
__device__ __forceinline__ float nofuse(float x) { asm volatile("" : "+v"(x)); return x; }

// numpy pairwise_sum for n=128 (its n<=PW_BLOCKSIZE path): 8 accumulators,
// r[j] = a[j] + a[8+j] + ... + a[120+j] (sequential), then
// ((r0+r1)+(r2+r3)) + ((r4+r5)+(r6+r7)). Squares rounded BEFORE adding
// (numpy computes z**2 elementwise first) — nofuse blocks fma fusion.
__global__ void rownorm_np(const float* __restrict__ a, float* __restrict__ out, int nrows) {
    int row = blockIdx.x * blockDim.x + threadIdx.x;
    if (row >= nrows) return;
    const float* p = a + (size_t)row * DDIM;
    float r[8];
    #pragma unroll
    for (int j = 0; j < 8; ++j) { float v = p[j]; r[j] = nofuse(v * v); }
    #pragma unroll
    for (int i = 8; i < DDIM; i += 8) {
        #pragma unroll
        for (int j = 0; j < 8; ++j) {
            float v = p[i + j];
            r[j] = nofuse(r[j] + nofuse(v * v));
        }
    }
    float s01 = nofuse(r[0] + r[1]);
    float s23 = nofuse(r[2] + r[3]);
    float s45 = nofuse(r[4] + r[5]);
    float s67 = nofuse(r[6] + r[7]);
    out[row] = nofuse(nofuse(s01 + s23) + nofuse(s45 + s67));
}

// ---------------- distances + argmin ----------------
// dist(t,k) = fl( fl(zn_t + cn_k) - 2*dot(z_t,c_k) )  — numpy fp32 semantics.
__global__ __launch_bounds__(256, 2)
void dist_argmin(const float* __restrict__ z, const float* __restrict__ cb,
                 const float* __restrict__ znorm, const float* __restrict__ cnorm,
                 int* __restrict__ idx_out, float* __restrict__ idxf_out) {
    // LDS carve: zt[DDIM][TP] | ct[DDIM][TP] | cn_s[KC] | zn_s[TT]
    __shared__ float smem[2 * DDIM * TP + KC + TT];
    float* zt   = smem;                    // [d][token], pitch TP
    float* ct   = smem + DDIM * TP;        // [d][code],  pitch TP
    float* cn_s = smem + 2 * DDIM * TP;    // [KC]
    float* zn_s = cn_s + KC;               // [TT]
    // reduction arrays alias ct after the K-loop (post-barrier)
    float* red_v = ct;                     // [TT*16]
    int*   red_i = (int*)(ct + TT * 16);   // [TT*16]

    const int tid = threadIdx.x;
    const int tx = tid & 15;   // code micro-col  (codes 4*tx..4*tx+3)
    const int ty = tid >> 4;   // token micro-row (tokens 4*ty..4*ty+3)
    const int t0 = blockIdx.x * TT;

    // stage z-tile transposed: zt[d][t]
    #pragma unroll
    for (int it = 0; it < 8; ++it) {
        int g  = it * 256 + tid;
        int d4 = g >> 6;
        int t  = g & 63;
        float4 v = *(const float4*)(z + (size_t)(t0 + t) * DDIM + d4 * 4);
        zt[(4 * d4 + 0) * TP + t] = v.x;
        zt[(4 * d4 + 1) * TP + t] = v.y;
        zt[(4 * d4 + 2) * TP + t] = v.z;
        zt[(4 * d4 + 3) * TP + t] = v.w;
    }
    if (tid < TT) zn_s[tid] = znorm[t0 + tid];

    float minv[4];
    int   mini[4];
    #pragma unroll
    for (int i = 0; i < 4; ++i) { minv[i] = FLT_MAX; mini[i] = 0; }

    for (int kc = 0; kc < KCODES; kc += KC) {
        __syncthreads();   // prev compute done (and zt/zn staged, first iter)
        #pragma unroll
        for (int it = 0; it < 8; ++it) {
            int g  = it * 256 + tid;
            int d4 = g >> 6;
            int c  = g & 63;
            float4 v = *(const float4*)(cb + (size_t)(kc + c) * DDIM + d4 * 4);
            ct[(4 * d4 + 0) * TP + c] = v.x;
            ct[(4 * d4 + 1) * TP + c] = v.y;
            ct[(4 * d4 + 2) * TP + c] = v.z;
            ct[(4 * d4 + 3) * TP + c] = v.w;
        }
        if (tid < KC) cn_s[tid] = cnorm[kc + tid];
        __syncthreads();

        float acc[4][4];
        #pragma unroll
        for (int i = 0; i < 4; ++i)
            #pragma unroll
            for (int j = 0; j < 4; ++j) acc[i][j] = 0.0f;

        #pragma unroll 8
        for (int d = 0; d < DDIM; ++d) {
            float4 a4 = *(const float4*)(zt + d * TP + 4 * ty);
            float4 b4 = *(const float4*)(ct + d * TP + 4 * tx);
            float ar[4] = {a4.x, a4.y, a4.z, a4.w};
            float br[4] = {b4.x, b4.y, b4.z, b4.w};
            #pragma unroll
            for (int i = 0; i < 4; ++i)
                #pragma unroll
                for (int j = 0; j < 4; ++j)
                    acc[i][j] = fmaf(ar[i], br[j], acc[i][j]);
        }

        #pragma unroll
        for (int j = 0; j < 4; ++j) {
            float cn = cn_s[4 * tx + j];
            int   kk = kc + 4 * tx + j;
            #pragma unroll
            for (int i = 0; i < 4; ++i) {
                // s = fl(zn + cn); dist = fl(s - 2*acc). fmaf(-2,acc,s) equals
                // the two-step result because 2*acc is exact (power of two).
                float s = nofuse(zn_s[4 * ty + i] + cn);
                float dist = fmaf(-2.0f, acc[i][j], s);
                // strict < keeps earliest (lowest) index; per-thread k ascends
                if (dist < minv[i]) { minv[i] = dist; mini[i] = kk; }
            }
        }
    }

    __syncthreads();   // done with ct — alias as reduction space
    #pragma unroll
    for (int i = 0; i < 4; ++i) {
        red_v[(4 * ty + i) * 16 + tx] = minv[i];
        red_i[(4 * ty + i) * 16 + tx] = mini[i];
    }
    __syncthreads();
    if (tid < TT) {
        int t = tid;
        float bv = red_v[t * 16];
        int   bi = red_i[t * 16];
        #pragma unroll
        for (int j = 1; j < 16; ++j) {
            float v  = red_v[t * 16 + j];
            int   ii = red_i[t * 16 + j];
            if (v < bv || (v == bv && ii < bi)) { bv = v; bi = ii; }
        }
        idx_out[t0 + t]  = bi;
        idxf_out[t0 + t] = (float)bi;
    }
}

// ---------------- gather z_q + per-block loss partials ----------------
__global__ void gather_loss(const float* __restrict__ z, const float* __restrict__ cb,
                            const int* __restrict__ idx,
                            float* __restrict__ zq, float* __restrict__ partials) {
    int t = blockIdx.x * 2 + (threadIdx.x >> 7);
    int d = threadIdx.x & 127;
    int k = idx[t];
    float q  = cb[(size_t)k * DDIM + d];
    float zv = z[(size_t)t * DDIM + d];
    zq[(size_t)t * DDIM + d] = q;
    float diff = q - zv;
    float s = diff * diff;
    #pragma unroll
    for (int off = 32; off > 0; off >>= 1) s += __shfl_down(s, off);
    __shared__ float sm[4];
    int lane = threadIdx.x & 63, wv = threadIdx.x >> 6;
    if (lane == 0) sm[wv] = s;
    __syncthreads();
    if (threadIdx.x == 0) partials[blockIdx.x] = sm[0] + sm[1] + sm[2] + sm[3];
}

// ---------------- final loss reduce ----------------
__global__ void loss_final(const float* __restrict__ partials, float* __restrict__ out_loss) {
    double s = 0.0;
    for (int i = threadIdx.x; i < NTOK / 2; i += 256) s += (double)partials[i];
    #pragma unroll
    for (int off = 32; off > 0; off >>= 1) s += __shfl_down(s, off);
    __shared__ double sm[4];
    int lane = threadIdx.x & 63, wv = threadIdx.x >> 6;
    if (lane == 0) sm[wv] = s;
    __syncthreads();
    if (threadIdx.x == 0) {
        double tot = sm[0] + sm[1] + sm[2] + sm[3];
        // vq_loss = (1 + 0.25) * mean((q - z)^2)
        out_loss[0] = (float)(tot * 1.25 / (double)((size_t)NTOK * DDIM));
    }
}

extern "C" void kernel_launch(void* const* d_in, const int* in_sizes, int n_in,
                              void* d_out, int out_size, void* d_ws, size_t ws_size,
                              hipStream_t stream) {
    const float* z  = (const float*)d_in[0];   // [32768,128]
    const float* cb = (const float*)d_in[1];   // [1024,128]
    float* out = (float*)d_out;
    float* zq    = out;                        // 4194304
    float* loss  = out + (size_t)NTOK * DDIM;  // 1
    float* idxf  = loss + 1;                   // 32768 (indices as float)

    float* cnorm    = (float*)d_ws;                          // 1024 f
    float* znorm    = cnorm + KCODES;                        // 32768 f
    int*   idx      = (int*)(znorm + NTOK);                  // 32768 i
    float* partials = (float*)(idx + NTOK);                  // 16384 f

    rownorm_np<<<KCODES / 256, 256, 0, stream>>>(cb, cnorm, KCODES);
    rownorm_np<<<NTOK / 256, 256, 0, stream>>>(z, znorm, NTOK);
    dist_argmin<<<NTOK / TT, 256, 0, stream>>>(z, cb, znorm, cnorm, idx, idxf);
    gather_loss<<<NTOK / 2, 256, 0, stream>>>(z, cb, idx, zq, partials);
    loss_final<<<1, 256, 0, stream>>>(partials, loss);
}